// Round 13
// baseline (2620.543 us; speedup 1.0000x reference)
//
#include <hip/hip_runtime.h>
#include <cstdint>
#include <cstddef>

// Replicate numpy f32 semantics: no compiler-introduced fusion anywhere.
// All intentional fusion is via explicit fmaf().
#pragma clang fp contract(off)

#define NROWS 32768          // B*C
#define NCOLS 2304           // 3*D_MODEL
#define DMODEL 768
#define QK 1536              // q+k columns
#define KCH 409
#define NBATCH 8
#define FEAT_ELEMS ((size_t)NBATCH * KCH * DMODEL)   // 2512896
#define SCALE_F 0.08838834764831845f                 // f32(128^-0.5)

#define BM 128
#define BN 128
#define BK 32

typedef float v4f __attribute__((ext_vector_type(4)));

// ---------------------------------------------------------------------------
// K1: qkv = x @ W^T + b, f32, bit-exact numpy/OpenBLAS semantics:
// ONE f32 accumulator per C element, k strictly ascending, fmaf chain, then
// a separate (non-fused) bias add.
//
// global_load_lds staging (m97 structure): transpose done on the GLOBAL side
// (per-lane gather addresses, m173); LDS writes are linear lane*16B ->
// conflict-free by construction. LDS layout [g][slot][4k], slot s=64h+lane
// holds row 8*(lane&15) + (lane>>4) + 4h, so
//   A-reads (slot ty+16i): 4 distinct addrs/wave, 16-lane broadcast (free)
//   B-reads (slot tx+16j): start-bank 4tx -> 2-way (free, m136)
// r12 BUG FIXED HERE: the builtin's offset immediate applies to BOTH the
// global AND LDS address (it's the instruction's single offset: field;
// LDS addr = M0 + offset + lane*16). r12 passed offset=16 with an already-
// advanced LDS base -> odd k-groups shifted one slot (slot 0 uninitialized,
// lane 63 overran the region) -> inf. Now offset=0 everywhere; the +16B k
// advance lives in the global pointer, the region advance in the LDS base.
// Double-buffered (64 KB), one barrier per tile. No staging registers, no
// scalar ds_writes. No v_pk_fma_f32 (r9: 6-8x slower than v_fmac).
// ---------------------------------------------------------------------------
__global__ __launch_bounds__(256) void gemm_qkv_f32(
    const float* __restrict__ x, const float* __restrict__ W,
    const float* __restrict__ bias, float* __restrict__ qkv)
{
    __shared__ __align__(16) float As[2][4096];   // [buf][g*512 + slot*4 + kq]
    __shared__ __align__(16) float Bs[2][4096];

    const int tid  = threadIdx.x;
    const int lane = tid & 63;
    const int wid  = tid >> 6;        // wave 0..3
    const int tx = tid & 15;          // output col group (8 cols)
    const int ty = tid >> 4;          // output row group (8 rows)
    const int n0 = blockIdx.x * BN;
    const int m0 = blockIdx.y * BM;

    // slot s=64h+lane holds row 8*(lane&15) + (lane>>4) + 4h
    const int rowoff = 8 * (lane & 15) + (lane >> 4);
    const float* pA0 = x + (size_t)(m0 + rowoff) * DMODEL + 8 * wid;
    const float* pA1 = x + (size_t)(m0 + rowoff + 4) * DMODEL + 8 * wid;
    const float* pB0 = W + (size_t)(n0 + rowoff) * DMODEL + 8 * wid;
    const float* pB1 = W + (size_t)(n0 + rowoff + 4) * DMODEL + 8 * wid;

    float acc[8][8] = {};

#define DMA16(gp, lp) \
    __builtin_amdgcn_global_load_lds( \
        (const __attribute__((address_space(1))) uint32_t*)(gp), \
        (__attribute__((address_space(3))) uint32_t*)(lp), 16, 0, 0)

    // wave wid stages k-groups g=2wid (k=8wid..8wid+3) and g=2wid+1
    // (k=8wid+4..8wid+7), halves h=0 (slots 0..63) / h=1 (slots 64..127):
    // 8 DMA per wave per tile, offset=0 on every call (see bug note above).
#define STAGE(buf) do { \
    float* Ab = &As[buf][(2 * wid) * 512]; \
    float* Bb = &Bs[buf][(2 * wid) * 512]; \
    DMA16(pA0,     Ab);        DMA16(pA1,     Ab + 256); \
    DMA16(pA0 + 4, Ab + 512);  DMA16(pA1 + 4, Ab + 768); \
    DMA16(pB0,     Bb);        DMA16(pB1,     Bb + 256); \
    DMA16(pB0 + 4, Bb + 512);  DMA16(pB1 + 4, Bb + 768); \
} while (0)

    STAGE(0);
    pA0 += BK; pA1 += BK; pB0 += BK; pB1 += BK;
    __syncthreads();   // compiler drains vmcnt(0) before the barrier

    for (int kt = 0; kt < DMODEL / BK; ++kt) {
        const int cb = kt & 1;
        if (kt + 1 < DMODEL / BK) {   // issue next tile; in flight during FMA
            STAGE(cb ^ 1);
            pA0 += BK; pA1 += BK; pB0 += BK; pB1 += BK;
        }

        #pragma unroll
        for (int g = 0; g < 8; ++g) {   // k = 4g..4g+3, ascending
            const float* Ag = &As[cb][g * 512 + 4 * ty];
            const float* Bg = &Bs[cb][g * 512 + 4 * tx];
            v4f a[8], b[8];
            #pragma unroll
            for (int i = 0; i < 8; ++i) a[i] = *(const v4f*)(Ag + 64 * i);
            #pragma unroll
            for (int j = 0; j < 8; ++j) b[j] = *(const v4f*)(Bg + 64 * j);
            #pragma unroll
            for (int kq = 0; kq < 4; ++kq)   // one fmaf chain per element
                #pragma unroll
                for (int i = 0; i < 8; ++i)
                    #pragma unroll
                    for (int j = 0; j < 8; ++j)
                        acc[i][j] = fmaf(a[i][kq], b[j][kq], acc[i][j]);
        }
        __syncthreads();
    }

    const int col = n0 + 8 * tx;
    float bcol[8];
    #pragma unroll
    for (int j = 0; j < 8; ++j) bcol[j] = bias[col + j];

    #pragma unroll
    for (int i = 0; i < 8; ++i) {
        const int row = m0 + 8 * ty + i;
        float4 o0, o1;
        o0.x = acc[i][0] + bcol[0];   // np: separate f32 add (non-fused)
        o0.y = acc[i][1] + bcol[1];
        o0.z = acc[i][2] + bcol[2];
        o0.w = acc[i][3] + bcol[3];
        o1.x = acc[i][4] + bcol[4];
        o1.y = acc[i][5] + bcol[5];
        o1.z = acc[i][6] + bcol[6];
        o1.w = acc[i][7] + bcol[7];
        *(float4*)(&qkv[(size_t)row * NCOLS + col])     = o0;
        *(float4*)(&qkv[(size_t)row * NCOLS + col + 4]) = o1;
    }
}

// ---------------------------------------------------------------------------
// K2: per row — f32 scores (non-fused mul+add, * SCALE_F) -> per-head argmax
// (tie -> lowest g); channel norm replicating np.linalg.norm(out_f32):
// f32 squares in feature order f=d*6+h, numpy pairwise tree
// 768 -> 2x384 -> 4x192 -> 8x96, 96-leaf = 8-accumulator unrolled loop,
// combine ((r0+r1)+(r2+r3))+((r4+r5)+(r6+r7)); sqrtf. 1 wave per row.
// ---------------------------------------------------------------------------
__global__ __launch_bounds__(256) void select_and_norm(
    const float* __restrict__ qkv, float* __restrict__ norms,
    uint64_t* __restrict__ gstar)
{
    __shared__ float rowbuf[4][NCOLS];
    __shared__ float sc[4][36];
    __shared__ int   gs_s[4][6];
    __shared__ float sblk[4][8];

    const int tid  = threadIdx.x;
    const int wave = tid >> 6;
    const int lane = tid & 63;
    const int n = blockIdx.x * 4 + wave;

    {
        const float4* src = (const float4*)(qkv + (size_t)n * NCOLS);
        float4* dst = (float4*)(&rowbuf[wave][0]);
        #pragma unroll
        for (int i = 0; i < 9; ++i) dst[lane + 64 * i] = src[lane + 64 * i];
    }
    __syncthreads();

    if (lane < 36) {
        const int h = lane / 6, g = lane % 6;
        const float* qh = &rowbuf[wave][h * 128];
        const float* kh = &rowbuf[wave][768 + g * 128];
        float s = 0.0f;
        for (int d = 0; d < 128; ++d)
            s = s + qh[d] * kh[d];        // np einsum: mul then add, d ascending
        sc[wave][lane] = s * SCALE_F;
    }
    __syncthreads();

    if (lane < 6) {
        float best = sc[wave][lane * 6];
        int bg = 0;
        #pragma unroll
        for (int g = 1; g < 6; ++g) {
            const float v = sc[wave][lane * 6 + g];
            if (v > best) { best = v; bg = g; }   // strict >: lowest g on tie
        }
        gs_s[wave][lane] = bg;
    }
    __syncthreads();

    if (lane < 8) {   // lane j: numpy pairwise 96-leaf over f in [96j, 96j+96)
        const float* vr = &rowbuf[wave][QK];
        int gtab[6];
        #pragma unroll
        for (int h = 0; h < 6; ++h) gtab[h] = gs_s[wave][h];

        float r8[8];
        #pragma unroll
        for (int jj = 0; jj < 8; ++jj) {
            const int f = 96 * lane + jj;
            const float v = vr[gtab[f % 6] * 128 + f / 6];
            r8[jj] = v * v;                       // rounded square (np temp)
        }
        for (int i = 8; i < 96; i += 8) {
            #pragma unroll
            for (int jj = 0; jj < 8; ++jj) {
                const int f = 96 * lane + i + jj;
                const float v = vr[gtab[f % 6] * 128 + f / 6];
                r8[jj] = r8[jj] + v * v;
            }
        }
        sblk[wave][lane] = ((r8[0] + r8[1]) + (r8[2] + r8[3]))
                         + ((r8[4] + r8[5]) + (r8[6] + r8[7]));
    }
    __syncthreads();

    if (lane == 0) {
        const float* s = sblk[wave];
        float n2 = ((s[0] + s[1]) + (s[2] + s[3]))
                 + ((s[4] + s[5]) + (s[6] + s[7]));   // 768->384->192->96 tree
        norms[n] = sqrtf(n2);                         // IEEE sqrt = np
        uint64_t pk = 0;
        #pragma unroll
        for (int h = 0; h < 6; ++h)
            pk |= (uint64_t)gs_s[wave][h] << (8 * h);
        gstar[n] = pk;
    }
}

// ---------------------------------------------------------------------------
// K3: per batch — top-409 channels by f32 norm, descending, tie -> lower idx.
// ---------------------------------------------------------------------------
__global__ __launch_bounds__(256) void topk_channels(
    const float* __restrict__ norms, int* __restrict__ chidx,
    float* __restrict__ out)
{
    __shared__ float vals[4096];
    __shared__ float rv[256];
    __shared__ int   ri[256];
    const int b = blockIdx.x, t = threadIdx.x;

    for (int i = t; i < 4096; i += 256)
        vals[i] = norms[(size_t)b * 4096 + i];
    __syncthreads();

    for (int j = 0; j < KCH; ++j) {
        float best = -1.0f;                  // norms >= 0
        int bi = 0;
        #pragma unroll
        for (int u = 0; u < 16; ++u) {
            const int i = t + 256 * u;       // ascending: strict > keeps lowest
            const float v = vals[i];
            if (v > best) { best = v; bi = i; }
        }
        rv[t] = best; ri[t] = bi;
        __syncthreads();
        for (int s2 = 128; s2 > 0; s2 >>= 1) {
            if (t < s2) {
                const float ov = rv[t + s2]; const int oi = ri[t + s2];
                if (ov > rv[t] || (ov == rv[t] && oi < ri[t])) { rv[t] = ov; ri[t] = oi; }
            }
            __syncthreads();
        }
        if (t == 0) {
            const int w = ri[0];
            chidx[b * KCH + j] = w;
            out[FEAT_ELEMS + (size_t)b * KCH + j] = (float)w;
            vals[w] = -1.0f;
        }
        __syncthreads();
    }
    if (b == 0 && t == 0)
        out[FEAT_ELEMS + (size_t)NBATCH * KCH] = (float)KCH;   // k_channels
}

// ---------------------------------------------------------------------------
// K4: sparse_feat[b,j,f] = v[n, g*(n, f%6), f/6], n = b*4096 + ch_idx[b,j]
// (f = d*6 + h interleave from the reference's swapaxes+reshape)
// ---------------------------------------------------------------------------
__global__ __launch_bounds__(256) void gather_sparse(
    const float* __restrict__ qkv, const uint64_t* __restrict__ gstar,
    const int* __restrict__ chidx, float* __restrict__ out)
{
    const int bj = blockIdx.x;
    const int b = bj / KCH;
    const int ch = chidx[bj];
    const int n = b * 4096 + ch;
    const uint64_t pk = gstar[n];
    for (int f = threadIdx.x; f < DMODEL; f += 256) {
        const int h = f % 6;
        const int d = f / 6;
        const int g = (int)((pk >> (8 * h)) & 7u);
        out[(size_t)bj * DMODEL + f] = qkv[(size_t)n * NCOLS + QK + g * 128 + d];
    }
}

// ---------------------------------------------------------------------------
extern "C" void kernel_launch(void* const* d_in, const int* in_sizes, int n_in,
                              void* d_out, int out_size, void* d_ws, size_t ws_size,
                              hipStream_t stream)
{
    const float* x    = (const float*)d_in[0];
    const float* W    = (const float*)d_in[1];
    const float* bias = (const float*)d_in[2];
    float* out = (float*)d_out;
    char*  ws  = (char*)d_ws;

    const size_t qkvBytes   = (size_t)NROWS * NCOLS * sizeof(float);   // ~302 MB
    const size_t normsBytes = (size_t)NROWS * sizeof(float);
    const size_t gstarBytes = (size_t)NROWS * sizeof(uint64_t);
    const size_t chidxBytes = (size_t)NBATCH * KCH * sizeof(int);
    const size_t baseBytes  = qkvBytes + normsBytes + gstarBytes + chidxBytes;
    if (ws_size < baseBytes) return;   // fail visibly rather than fault

    float*    qkv   = (float*)ws;
    float*    norms = (float*)(ws + qkvBytes);
    uint64_t* gstar = (uint64_t*)(ws + qkvBytes + normsBytes);
    int*      chidx = (int*)(ws + qkvBytes + normsBytes + gstarBytes);

    gemm_qkv_f32<<<dim3(NCOLS / BN, NROWS / BM), 256, 0, stream>>>(x, W, bias, qkv);
    select_and_norm<<<NROWS / 4, 256, 0, stream>>>(qkv, norms, gstar);
    topk_channels<<<NBATCH, 256, 0, stream>>>(norms, chidx, out);
    gather_sparse<<<NBATCH * KCH, 256, 0, stream>>>(qkv, gstar, chidx, out);
}

// Round 14
// 1998.510 us; speedup vs baseline: 1.3112x; 1.3112x over previous
//
#include <hip/hip_runtime.h>
#include <cstdint>
#include <cstddef>

// Replicate numpy f32 semantics: no compiler-introduced fusion anywhere.
// All intentional fusion is via explicit fmaf().
#pragma clang fp contract(off)

#define NROWS 32768          // B*C
#define NCOLS 2304           // 3*D_MODEL
#define DMODEL 768
#define QK 1536              // q+k columns
#define KCH 409
#define NBATCH 8
#define FEAT_ELEMS ((size_t)NBATCH * KCH * DMODEL)   // 2512896
#define SCALE_F 0.08838834764831845f                 // f32(128^-0.5)

#define BM 128
#define BN 128
#define BK 32
#define RS 140     // LDS k-row stride in floats (16 chunks, spread layout)
#define LSZ 4512   // BK*RS + max skew (31*140 + 28 + 139 + 1 -> padded)

typedef float v4f __attribute__((ext_vector_type(4)));

// chunk c (8 floats) -> float offset within an LDS k-row (+4*(c>>2) spread).
__device__ __forceinline__ int chunk_off(int c) { return 8 * c + 4 * (c >> 2); }

// ---------------------------------------------------------------------------
// K1: qkv = x @ W^T + b, f32, bit-exact numpy/OpenBLAS semantics:
// ONE f32 accumulator per C element, k strictly ascending, fmaf chain, then
// a separate (non-fused) bias add. r6 structure (128x128, BK=32, 256 thr,
// 8x8/thread, VGPR ~76 -> ~33% occupancy) + k-group write-deskew:
//
// Staging store banks in r6 were (kk*RS mod 32) + wsub = {0,16}+wsub -> 4-way
// (1.98e8 conflict-cycles, ~320us). Fix: k-group t stores at +4t floats;
// banks become 20t + wsub + C -> all-32-bank 2-way (free, m136). Reads
// compensate with +4*(k>>2), which is LANE-UNIFORM and k is fully unrolled,
// so it folds into each ds_read's immediate offset: zero extra VGPRs, zero
// occupancy change, read bank pattern unchanged (uniform shift per k).
// History: r7-r11 reg-staging variants paid VGPR/occupancy; r13 DMA staging
// had 0 conflicts but 1 block/CU (latency-exposed). No v_pk_fma_f32 (r9).
// ---------------------------------------------------------------------------
__global__ __launch_bounds__(256) void gemm_qkv_f32(
    const float* __restrict__ x, const float* __restrict__ W,
    const float* __restrict__ bias, float* __restrict__ qkv)
{
    __shared__ float As[LSZ];
    __shared__ float Bs[LSZ];

    const int tid = threadIdx.x;
    const int tx = tid & 15;          // output col chunk (8 cols)
    const int ty = tid >> 4;          // output row chunk (8 rows)
    const int n0 = blockIdx.x * BN;
    const int m0 = blockIdx.y * BM;

    const int sm  = tid >> 3;         // staging row 0..31 (+32 per batch)
    const int t8  = tid & 7;          // k-group lane
    const int sk4 = t8 << 2;          // staging k offset 0,4,...,28
    const int wsub = sm & 7;
    const int wchk = sm >> 3;         // 0..3

    const float* xa = x + (size_t)(m0 + sm) * DMODEL + sk4;
    const float* wb = W + (size_t)(n0 + sm) * DMODEL + sk4;

    // staging write offsets; +4*t8 deskew spreads k-group bank-starts
    int co[4];
    #pragma unroll
    for (int i = 0; i < 4; ++i) co[i] = chunk_off(wchk + 4 * i) + wsub + 4 * t8;

    float4 pa[4], pb[4];
    #pragma unroll
    for (int i = 0; i < 4; ++i) {
        pa[i] = *(const float4*)(xa + (size_t)(32 * i) * DMODEL);
        pb[i] = *(const float4*)(wb + (size_t)(32 * i) * DMODEL);
    }

    float acc[8][8] = {};

    for (int kt = 0; kt < DMODEL / BK; ++kt) {
        __syncthreads();   // previous iteration's LDS reads complete
        #pragma unroll
        for (int i = 0; i < 4; ++i) {
            As[(sk4 + 0) * RS + co[i]] = pa[i].x;
            As[(sk4 + 1) * RS + co[i]] = pa[i].y;
            As[(sk4 + 2) * RS + co[i]] = pa[i].z;
            As[(sk4 + 3) * RS + co[i]] = pa[i].w;
            Bs[(sk4 + 0) * RS + co[i]] = pb[i].x;
            Bs[(sk4 + 1) * RS + co[i]] = pb[i].y;
            Bs[(sk4 + 2) * RS + co[i]] = pb[i].z;
            Bs[(sk4 + 3) * RS + co[i]] = pb[i].w;
        }
        __syncthreads();

        if (kt + 1 < DMODEL / BK) {   // prefetch next K-tile; overlaps compute
            const int ko = (kt + 1) * BK;
            #pragma unroll
            for (int i = 0; i < 4; ++i) {
                pa[i] = *(const float4*)(xa + (size_t)(32 * i) * DMODEL + ko);
                pb[i] = *(const float4*)(wb + (size_t)(32 * i) * DMODEL + ko);
            }
        }

        const float* Ap = &As[chunk_off(ty)];
        const float* Bp = &Bs[chunk_off(tx)];
        #pragma unroll
        for (int k = 0; k < BK; ++k) {   // k ascending: one fmaf chain/element
            const int koff = k * RS + 4 * (k >> 2);   // +deskew (imm offset)
            const v4f a0 = *(const v4f*)(Ap + koff);
            const v4f a1 = *(const v4f*)(Ap + koff + 4);
            const v4f b0 = *(const v4f*)(Bp + koff);
            const v4f b1 = *(const v4f*)(Bp + koff + 4);
            const float a[8] = {a0.x, a0.y, a0.z, a0.w, a1.x, a1.y, a1.z, a1.w};
            const float b[8] = {b0.x, b0.y, b0.z, b0.w, b1.x, b1.y, b1.z, b1.w};
            #pragma unroll
            for (int i = 0; i < 8; ++i)
                #pragma unroll
                for (int j = 0; j < 8; ++j)
                    acc[i][j] = fmaf(a[i], b[j], acc[i][j]);
        }
    }

    const int col = n0 + 8 * tx;
    float bcol[8];
    #pragma unroll
    for (int j = 0; j < 8; ++j) bcol[j] = bias[col + j];

    #pragma unroll
    for (int i = 0; i < 8; ++i) {
        const int row = m0 + 8 * ty + i;
        float4 o0, o1;
        o0.x = acc[i][0] + bcol[0];   // np: separate f32 add (non-fused)
        o0.y = acc[i][1] + bcol[1];
        o0.z = acc[i][2] + bcol[2];
        o0.w = acc[i][3] + bcol[3];
        o1.x = acc[i][4] + bcol[4];
        o1.y = acc[i][5] + bcol[5];
        o1.z = acc[i][6] + bcol[6];
        o1.w = acc[i][7] + bcol[7];
        *(float4*)(&qkv[(size_t)row * NCOLS + col])     = o0;
        *(float4*)(&qkv[(size_t)row * NCOLS + col + 4]) = o1;
    }
}

// ---------------------------------------------------------------------------
// K2: per row — f32 scores (non-fused mul+add, * SCALE_F) -> per-head argmax
// (tie -> lowest g); channel norm replicating np.linalg.norm(out_f32):
// f32 squares in feature order f=d*6+h, numpy pairwise tree
// 768 -> 2x384 -> 4x192 -> 8x96, 96-leaf = 8-accumulator unrolled loop,
// combine ((r0+r1)+(r2+r3))+((r4+r5)+(r6+r7)); sqrtf. 1 wave per row.
// ---------------------------------------------------------------------------
__global__ __launch_bounds__(256) void select_and_norm(
    const float* __restrict__ qkv, float* __restrict__ norms,
    uint64_t* __restrict__ gstar)
{
    __shared__ float rowbuf[4][NCOLS];
    __shared__ float sc[4][36];
    __shared__ int   gs_s[4][6];
    __shared__ float sblk[4][8];

    const int tid  = threadIdx.x;
    const int wave = tid >> 6;
    const int lane = tid & 63;
    const int n = blockIdx.x * 4 + wave;

    {
        const float4* src = (const float4*)(qkv + (size_t)n * NCOLS);
        float4* dst = (float4*)(&rowbuf[wave][0]);
        #pragma unroll
        for (int i = 0; i < 9; ++i) dst[lane + 64 * i] = src[lane + 64 * i];
    }
    __syncthreads();

    if (lane < 36) {
        const int h = lane / 6, g = lane % 6;
        const float* qh = &rowbuf[wave][h * 128];
        const float* kh = &rowbuf[wave][768 + g * 128];
        float s = 0.0f;
        for (int d = 0; d < 128; ++d)
            s = s + qh[d] * kh[d];        // np einsum: mul then add, d ascending
        sc[wave][lane] = s * SCALE_F;
    }
    __syncthreads();

    if (lane < 6) {
        float best = sc[wave][lane * 6];
        int bg = 0;
        #pragma unroll
        for (int g = 1; g < 6; ++g) {
            const float v = sc[wave][lane * 6 + g];
            if (v > best) { best = v; bg = g; }   // strict >: lowest g on tie
        }
        gs_s[wave][lane] = bg;
    }
    __syncthreads();

    if (lane < 8) {   // lane j: numpy pairwise 96-leaf over f in [96j, 96j+96)
        const float* vr = &rowbuf[wave][QK];
        int gtab[6];
        #pragma unroll
        for (int h = 0; h < 6; ++h) gtab[h] = gs_s[wave][h];

        float r8[8];
        #pragma unroll
        for (int jj = 0; jj < 8; ++jj) {
            const int f = 96 * lane + jj;
            const float v = vr[gtab[f % 6] * 128 + f / 6];
            r8[jj] = v * v;                       // rounded square (np temp)
        }
        for (int i = 8; i < 96; i += 8) {
            #pragma unroll
            for (int jj = 0; jj < 8; ++jj) {
                const int f = 96 * lane + i + jj;
                const float v = vr[gtab[f % 6] * 128 + f / 6];
                r8[jj] = r8[jj] + v * v;
            }
        }
        sblk[wave][lane] = ((r8[0] + r8[1]) + (r8[2] + r8[3]))
                         + ((r8[4] + r8[5]) + (r8[6] + r8[7]));
    }
    __syncthreads();

    if (lane == 0) {
        const float* s = sblk[wave];
        float n2 = ((s[0] + s[1]) + (s[2] + s[3]))
                 + ((s[4] + s[5]) + (s[6] + s[7]));   // 768->384->192->96 tree
        norms[n] = sqrtf(n2);                         // IEEE sqrt = np
        uint64_t pk = 0;
        #pragma unroll
        for (int h = 0; h < 6; ++h)
            pk |= (uint64_t)gs_s[wave][h] << (8 * h);
        gstar[n] = pk;
    }
}

// ---------------------------------------------------------------------------
// K3: per batch — top-409 channels by f32 norm, descending, tie -> lower idx.
// ---------------------------------------------------------------------------
__global__ __launch_bounds__(256) void topk_channels(
    const float* __restrict__ norms, int* __restrict__ chidx,
    float* __restrict__ out)
{
    __shared__ float vals[4096];
    __shared__ float rv[256];
    __shared__ int   ri[256];
    const int b = blockIdx.x, t = threadIdx.x;

    for (int i = t; i < 4096; i += 256)
        vals[i] = norms[(size_t)b * 4096 + i];
    __syncthreads();

    for (int j = 0; j < KCH; ++j) {
        float best = -1.0f;                  // norms >= 0
        int bi = 0;
        #pragma unroll
        for (int u = 0; u < 16; ++u) {
            const int i = t + 256 * u;       // ascending: strict > keeps lowest
            const float v = vals[i];
            if (v > best) { best = v; bi = i; }
        }
        rv[t] = best; ri[t] = bi;
        __syncthreads();
        for (int s2 = 128; s2 > 0; s2 >>= 1) {
            if (t < s2) {
                const float ov = rv[t + s2]; const int oi = ri[t + s2];
                if (ov > rv[t] || (ov == rv[t] && oi < ri[t])) { rv[t] = ov; ri[t] = oi; }
            }
            __syncthreads();
        }
        if (t == 0) {
            const int w = ri[0];
            chidx[b * KCH + j] = w;
            out[FEAT_ELEMS + (size_t)b * KCH + j] = (float)w;
            vals[w] = -1.0f;
        }
        __syncthreads();
    }
    if (b == 0 && t == 0)
        out[FEAT_ELEMS + (size_t)NBATCH * KCH] = (float)KCH;   // k_channels
}

// ---------------------------------------------------------------------------
// K4: sparse_feat[b,j,f] = v[n, g*(n, f%6), f/6], n = b*4096 + ch_idx[b,j]
// (f = d*6 + h interleave from the reference's swapaxes+reshape)
// ---------------------------------------------------------------------------
__global__ __launch_bounds__(256) void gather_sparse(
    const float* __restrict__ qkv, const uint64_t* __restrict__ gstar,
    const int* __restrict__ chidx, float* __restrict__ out)
{
    const int bj = blockIdx.x;
    const int b = bj / KCH;
    const int ch = chidx[bj];
    const int n = b * 4096 + ch;
    const uint64_t pk = gstar[n];
    for (int f = threadIdx.x; f < DMODEL; f += 256) {
        const int h = f % 6;
        const int d = f / 6;
        const int g = (int)((pk >> (8 * h)) & 7u);
        out[(size_t)bj * DMODEL + f] = qkv[(size_t)n * NCOLS + QK + g * 128 + d];
    }
}

// ---------------------------------------------------------------------------
extern "C" void kernel_launch(void* const* d_in, const int* in_sizes, int n_in,
                              void* d_out, int out_size, void* d_ws, size_t ws_size,
                              hipStream_t stream)
{
    const float* x    = (const float*)d_in[0];
    const float* W    = (const float*)d_in[1];
    const float* bias = (const float*)d_in[2];
    float* out = (float*)d_out;
    char*  ws  = (char*)d_ws;

    const size_t qkvBytes   = (size_t)NROWS * NCOLS * sizeof(float);   // ~302 MB
    const size_t normsBytes = (size_t)NROWS * sizeof(float);
    const size_t gstarBytes = (size_t)NROWS * sizeof(uint64_t);
    const size_t chidxBytes = (size_t)NBATCH * KCH * sizeof(int);
    const size_t baseBytes  = qkvBytes + normsBytes + gstarBytes + chidxBytes;
    if (ws_size < baseBytes) return;   // fail visibly rather than fault

    float*    qkv   = (float*)ws;
    float*    norms = (float*)(ws + qkvBytes);
    uint64_t* gstar = (uint64_t*)(ws + qkvBytes + normsBytes);
    int*      chidx = (int*)(ws + qkvBytes + normsBytes + gstarBytes);

    gemm_qkv_f32<<<dim3(NCOLS / BN, NROWS / BM), 256, 0, stream>>>(x, W, bias, qkv);
    select_and_norm<<<NROWS / 4, 256, 0, stream>>>(qkv, norms, gstar);
    topk_channels<<<NBATCH, 256, 0, stream>>>(norms, chidx, out);
    gather_sparse<<<NBATCH * KCH, 256, 0, stream>>>(qkv, gstar, chidx, out);
}